// Round 3
// baseline (509.530 us; speedup 1.0000x reference)
//
#include <hip/hip_runtime.h>
#include <hip/hip_bf16.h>
#include <stdint.h>

// Problem: B=64, L=1024, V=1024, H=512, A=512
// out[0:65536)   = att_output [64][1024] fp32
// out[65536:...) = att_scores [64][1024] fp32

typedef __attribute__((ext_vector_type(8))) short bf16x8;
typedef __attribute__((ext_vector_type(8))) unsigned short ushortx8;
typedef __attribute__((ext_vector_type(4))) float f32x4;

#define LOG2E 1.4426950408889634f

__device__ __forceinline__ unsigned short f2bf(float f) {
  uint32_t u = __builtin_bit_cast(uint32_t, f);
  u += 0x7FFFu + ((u >> 16) & 1u);   // round-to-nearest-even
  return (unsigned short)(u >> 16);
}

__device__ __forceinline__ float fast_tanh(float x) {
  // tanh(x) = 1 - 2/(exp(2x)+1); exp via native exp2
  float e = __builtin_amdgcn_exp2f(x * 2.885390081777927f);  // 2*log2(e)
  return 1.0f - 2.0f * __builtin_amdgcn_rcpf(e + 1.0f);
}

__device__ __forceinline__ void load_lds16(const void* g, void* l) {
  __builtin_amdgcn_global_load_lds(
      (const __attribute__((address_space(1))) void*)g,
      (__attribute__((address_space(3))) void*)l, 16, 0, 0);
}

// ---------------------------------------------------------------------------
// K01: prep kernel, grid 512.
//  blocks [0,256):  pack W_enc [1024k][512a] fp32 -> Wst bf16, layout [t][kb][a]
//  blocks [256,512): zero att_output; dproj[b][a] = dec@W_dec + b_dec + b_enc
// ---------------------------------------------------------------------------
__global__ __launch_bounds__(256) void k01_prep(const float* __restrict__ W,
                                                unsigned short* __restrict__ Wst,
                                                const float* __restrict__ dec,
                                                const float* __restrict__ Wd,
                                                const float* __restrict__ bd,
                                                const float* __restrict__ be,
                                                float* __restrict__ dproj,
                                                float* __restrict__ out) {
  const int tid = threadIdx.x;
  if (blockIdx.x < 256) {
    const int S = blockIdx.x * 256 + tid;  // 65536 slots
    const int t = S >> 11;
    const int kb = (S >> 9) & 3;
    const int a = S & 511;
    const int k0 = t * 32 + kb * 8;
    ushortx8 p;
#pragma unroll
    for (int j = 0; j < 8; ++j) p[j] = f2bf(W[(size_t)(k0 + j) * 512 + a]);
    *(ushortx8*)(Wst + (size_t)S * 8) = p;
  } else {
    const int q = blockIdx.x - 256;  // 0..255
    out[q * 256 + tid] = 0.0f;       // zero att_output for k34's atomics
    const int b = q >> 2;
    const int a = (q & 3) * 128 + (tid & 127);
    const int hh = tid >> 7;         // 2 h-halves of 256
    const float* dr = dec + b * 512 + hh * 256;
    const float* wc = Wd + (size_t)(hh * 256) * 512 + a;
    float acc = 0.f;
#pragma unroll 8
    for (int h = 0; h < 256; ++h) acc = fmaf(dr[h], wc[(size_t)h * 512], acc);
    __shared__ float sh[128];
    if (hh == 1) sh[tid & 127] = acc;
    __syncthreads();
    if (hh == 0) dproj[b * 512 + a] = acc + sh[tid] + bd[a] + be[a];
  }
}

// ---------------------------------------------------------------------------
// K2: fused  logits[b,l] = sum_a w_full[a]*tanh( (vis@W_enc)[b,l,a] + dproj[b,a] )
// 128M x 512N per block, 512 threads = 8 waves (2 wm x 4 wn), wave tile 64x128.
// T14 depth-1 schedule: barrier -> issue A(t+1) HBM loads + B(t+1)
// global_load_lds -> MFMA on buf[cur] -> cvt+ds_write A(t+1).  All VMEM is
// ~1200cy old at the barrier's forced vmcnt(0) drain (>900cy HBM latency).
// Epilogue: LDS reduce of wn-partials -> plain coalesced logits stores.
// ---------------------------------------------------------------------------
__global__ __launch_bounds__(512, 1) void k2_fused_gemm(
    const float* __restrict__ vis, const unsigned short* __restrict__ Wst,
    const float* __restrict__ dproj, const float* __restrict__ wfull,
    float* __restrict__ logits) {
  alignas(16) __shared__ unsigned short Al[2][4096];
  alignas(16) __shared__ unsigned short Bl[2][16384];

  const int tid = threadIdx.x;
  const int lane = tid & 63;
  const int w = tid >> 6;
  const int wm = w >> 2;
  const int wn = w & 3;
  const int blk = blockIdx.x;
  const int b = blk >> 3;
  const size_t mbase = (size_t)blk * 128;

  const int arow = tid >> 2;
  const int akb = tid & 3;
  const float* asrc = vis + (mbase + (size_t)arow) * 1024 + akb * 8;
  const int a_dst = akb * 1024 + arow * 8;

  const unsigned short* bsrc = Wst + (size_t)w * 2048 + (size_t)lane * 8;

  f32x4 acc[4][8];
#pragma unroll
  for (int m = 0; m < 4; ++m)
#pragma unroll
    for (int n = 0; n < 8; ++n) acc[m][n] = (f32x4){0.f, 0.f, 0.f, 0.f};

  const int a_rd = (lane >> 4) * 1024 + (wm * 64 + (lane & 15)) * 8;
  const int b_rd = (lane >> 4) * 4096 + (wn * 128 + (lane & 15)) * 8;

  f32x4 xA0, xA1;
  // prologue: stage tile 0
  xA0 = *(const f32x4*)(asrc);
  xA1 = *(const f32x4*)(asrc + 4);
#pragma unroll
  for (int j = 0; j < 4; ++j)
    load_lds16(bsrc + j * 512, &Bl[0][w * 2048 + j * 512]);
  {
    ushortx8 p;
    p[0] = f2bf(xA0[0]); p[1] = f2bf(xA0[1]); p[2] = f2bf(xA0[2]); p[3] = f2bf(xA0[3]);
    p[4] = f2bf(xA1[0]); p[5] = f2bf(xA1[1]); p[6] = f2bf(xA1[2]); p[7] = f2bf(xA1[3]);
    *(ushortx8*)(&Al[0][a_dst]) = p;
  }

  for (int t = 0; t < 32; ++t) {
    const int cur = t & 1;
    __syncthreads();                        // buf[cur] ready; drain is ~free (T14)
    if (t < 31) {
      const float* as = asrc + (size_t)(t + 1) * 32;
      xA0 = *(const f32x4*)(as);            // issue HBM loads earliest
      xA1 = *(const f32x4*)(as + 4);
      const unsigned short* bs = bsrc + (size_t)(t + 1) * 16384;
#pragma unroll
      for (int j = 0; j < 4; ++j)
        load_lds16(bs + j * 512, &Bl[cur ^ 1][w * 2048 + j * 512]);
    }
    bf16x8 af[4];
#pragma unroll
    for (int m = 0; m < 4; ++m) af[m] = *(const bf16x8*)(&Al[cur][a_rd + m * 128]);
    bf16x8 bfr[8];
#pragma unroll
    for (int n = 0; n < 8; ++n) bfr[n] = *(const bf16x8*)(&Bl[cur][b_rd + n * 128]);
#pragma unroll
    for (int m = 0; m < 4; ++m)
#pragma unroll
      for (int n = 0; n < 8; ++n)
        acc[m][n] = __builtin_amdgcn_mfma_f32_16x16x32_bf16(af[m], bfr[n], acc[m][n], 0, 0, 0);
    if (t < 31) {                           // consume-late: cvt waits aload(t+1)
      ushortx8 p;
      p[0] = f2bf(xA0[0]); p[1] = f2bf(xA0[1]); p[2] = f2bf(xA0[2]); p[3] = f2bf(xA0[3]);
      p[4] = f2bf(xA1[0]); p[5] = f2bf(xA1[1]); p[6] = f2bf(xA1[2]); p[7] = f2bf(xA1[3]);
      *(ushortx8*)(&Al[cur ^ 1][a_dst]) = p;
    }
  }

  const float* dp = dproj + b * 512 + wn * 128 + (lane & 15);
  const float* wf = wfull + wn * 128 + (lane & 15);
  float dpv[8], wfv[8];
#pragma unroll
  for (int n = 0; n < 8; ++n) { dpv[n] = dp[n * 16]; wfv[n] = wf[n * 16]; }

  float* Lred = (float*)Al;   // [128 rows][4 wn] overlay
  __syncthreads();            // all frag reads done before LDS reuse

#pragma unroll
  for (int m = 0; m < 4; ++m) {
#pragma unroll
    for (int r = 0; r < 4; ++r) {
      float s = 0.f;
#pragma unroll
      for (int n = 0; n < 8; ++n)
        s += wfv[n] * fast_tanh(acc[m][n][r] + dpv[n]);
      s += __shfl_xor(s, 1, 64);
      s += __shfl_xor(s, 2, 64);
      s += __shfl_xor(s, 4, 64);
      s += __shfl_xor(s, 8, 64);
      if ((lane & 15) == 0) {
        int row = wm * 64 + m * 16 + (lane >> 4) * 4 + r;
        Lred[row * 4 + wn] = s;
      }
    }
  }
  __syncthreads();
  if (tid < 128) {
    f32x4 v = *(const f32x4*)(&Lred[tid * 4]);
    logits[mbase + tid] = v[0] + v[1] + v[2] + v[3];
  }
}

// ---------------------------------------------------------------------------
// K34: fused softmax + weighted sum. grid (64 b, 8 chunks of 128 l).
// ---------------------------------------------------------------------------
__global__ __launch_bounds__(256) void k34_attout(const float* __restrict__ logits,
                                                  const float* __restrict__ vis,
                                                  float* __restrict__ out) {
  const int b = blockIdx.x;
  const int chunk = blockIdx.y;
  const int tid = threadIdx.x;
  const int wid = tid >> 6;
  const int lane = tid & 63;
  const float* base = logits + b * 1024;

  float x[4];
#pragma unroll
  for (int j = 0; j < 4; ++j) x[j] = base[j * 256 + tid];
  float mx = fmaxf(fmaxf(x[0], x[1]), fmaxf(x[2], x[3]));
#pragma unroll
  for (int d = 1; d < 64; d <<= 1) mx = fmaxf(mx, __shfl_xor(mx, d, 64));
  __shared__ float redm[4], reds[4];
  if (lane == 0) redm[wid] = mx;
  __syncthreads();
  mx = fmaxf(fmaxf(redm[0], redm[1]), fmaxf(redm[2], redm[3]));
  float s = 0.f;
#pragma unroll
  for (int j = 0; j < 4; ++j) s += __builtin_amdgcn_exp2f((x[j] - mx) * LOG2E);
#pragma unroll
  for (int d = 1; d < 64; d <<= 1) s += __shfl_xor(s, d, 64);
  if (lane == 0) reds[wid] = s;
  __syncthreads();
  s = reds[0] + reds[1] + reds[2] + reds[3];
  const float inv = 1.0f / s;

  if (chunk == 0) {
#pragma unroll
    for (int j = 0; j < 4; ++j)
      out[65536 + b * 1024 + j * 256 + tid] =
          __builtin_amdgcn_exp2f((x[j] - mx) * LOG2E) * inv;
  }

  __shared__ float p[128];
  const int l0 = chunk * 128;
  if (tid < 128)
    p[tid] = __builtin_amdgcn_exp2f((base[l0 + tid] - mx) * LOG2E) * inv;
  __syncthreads();

  const f32x4* vb = (const f32x4*)(vis + ((size_t)b * 1024 + (size_t)l0) * 1024) + tid;
  f32x4 acc0 = (f32x4){0.f, 0.f, 0.f, 0.f};
  f32x4 acc1 = (f32x4){0.f, 0.f, 0.f, 0.f};
#pragma unroll 4
  for (int l = 0; l < 128; l += 2) {
    acc0 += vb[(size_t)l * 256] * p[l];
    acc1 += vb[(size_t)(l + 1) * 256] * p[l + 1];
  }
  f32x4 acc = acc0 + acc1;
  float* o = out + b * 1024 + tid * 4;
  atomicAdd(o + 0, acc[0]);
  atomicAdd(o + 1, acc[1]);
  atomicAdd(o + 2, acc[2]);
  atomicAdd(o + 3, acc[3]);
}

extern "C" void kernel_launch(void* const* d_in, const int* in_sizes, int n_in,
                              void* d_out, int out_size, void* d_ws, size_t ws_size,
                              hipStream_t stream) {
  const float* vis = (const float*)d_in[0];
  const float* dec = (const float*)d_in[1];
  const float* Wenc = (const float*)d_in[2];
  const float* benc = (const float*)d_in[3];
  const float* Wdec = (const float*)d_in[4];
  const float* bdec = (const float*)d_in[5];
  const float* wfull = (const float*)d_in[6];
  // d_in[7] = b_full: softmax-shift-invariant -> unused.
  float* out = (float*)d_out;
  char* ws = (char*)d_ws;
  unsigned short* Wst = (unsigned short*)ws;
  float* dproj = (float*)(ws + (1 << 20));
  float* logits = (float*)(ws + (1 << 20) + (128 << 10));

  hipLaunchKernelGGL(k01_prep, dim3(512), dim3(256), 0, stream,
                     Wenc, Wst, dec, Wdec, bdec, benc, dproj, out);
  hipLaunchKernelGGL(k2_fused_gemm, dim3(512), dim3(512), 0, stream,
                     vis, Wst, dproj, wfull, logits);
  hipLaunchKernelGGL(k34_attout, dim3(64, 8), dim3(256), 0, stream,
                     logits, vis, out);
}